// Round 9
// baseline (206.571 us; speedup 1.0000x reference)
//
#include <hip/hip_runtime.h>
#include <stdint.h>

#define Bc 2
#define Tc 2048
#define Cn 1024
#define Hc 16
#define CAc 64

typedef __attribute__((ext_vector_type(8))) short short8;
typedef __attribute__((ext_vector_type(4))) float f32x4;

// 0.125 (1/sqrt(64)) * log2(e): folded into q so attention uses exp2 directly.
#define QSCALE 0.18033688011112042f

__device__ __forceinline__ unsigned short f2bf(float f) {
    unsigned int u = __builtin_bit_cast(unsigned int, f);
    return (unsigned short)((u + 0x7fffu + ((u >> 16) & 1u)) >> 16);
}
__device__ __forceinline__ unsigned int pack_rne(float a, float b) {
    return (unsigned int)f2bf(a) | ((unsigned int)f2bf(b) << 16);
}
// truncating bf16x2 pack in ONE v_perm_b32 (bias cancels in the P/sum ratio)
__device__ __forceinline__ unsigned int pack_trunc(float a, float b) {
    return __builtin_amdgcn_perm(__builtin_bit_cast(unsigned int, b),
                                 __builtin_bit_cast(unsigned int, a), 0x07060302u);
}

// async global->LDS, 16B per lane; HW scatters lane i to lds_base + i*16
__device__ __forceinline__ void async_cp16(const unsigned short* g, unsigned short* l) {
    __builtin_amdgcn_global_load_lds(
        (const __attribute__((address_space(1))) unsigned int*)g,
        (__attribute__((address_space(3))) unsigned int*)l,
        16, 0, 0);
}

// Self-detect input dtype from x (identical result in every block; uniform
// branch; reads hit the same L2 lines everywhere). 1 -> bf16, 0 -> f32.
__device__ __forceinline__ int detect_bf16(const unsigned short* x) {
    int c = 0;
#pragma unroll
    for (int i = 0; i < 64; i++) {
        unsigned short u = x[i * 2];           // even indices: f32 mantissa halves
        int e = (u >> 7) & 0xFF;
        c += (e >= 0x68 && e <= 0x90);
    }
    return c > 32;
}

__device__ __forceinline__ unsigned short ld_elem(const void* base, size_t off, int isbf) {
    return isbf ? ((const unsigned short*)base)[off] : f2bf(((const float*)base)[off]);
}

// ---------------------------------------------------------------------------
// prep: blocks [0,4096): convert x -> xb (skipped when x is bf16 — gemm_qkv
// reads x directly then). [4096,7168): transpose w_q/w_k/w_v. [7168,8192): w_o.
// ---------------------------------------------------------------------------
__global__ __launch_bounds__(256) void prep(
    const void* __restrict__ xin, unsigned short* __restrict__ xb,
    const void* __restrict__ wq, const void* __restrict__ wk,
    const void* __restrict__ wv, const void* __restrict__ wo,
    unsigned short* __restrict__ wT, unsigned short* __restrict__ woT)
{
    const int isbf = detect_bf16((const unsigned short*)xin);
    const int bx = blockIdx.x;
    if (bx < 4096) {
        if (isbf) return;                       // gemm reads x directly
        int idx = (bx * 256 + threadIdx.x) * 4;
        const float* xf = (const float*)xin;
        float4 v = *(const float4*)(xf + idx);
        uint2 p;
        p.x = pack_rne(v.x, v.y);
        p.y = pack_rne(v.z, v.w);
        *(uint2*)(&xb[idx]) = p;
        return;
    }
    __shared__ unsigned short tile[32][33];
    const int t = threadIdx.x;
    const int tx = t & 31, ty = t >> 5;
    const void* src;
    unsigned short* dst;
    int R, Cw, r0, c0;
    if (bx < 7168) {
        int rem0 = bx - 4096;
        int g = rem0 >> 6;            // proj*16 + h
        int rem = rem0 & 63;
        int ct = rem >> 1;
        int at = rem & 1;
        int proj = g >> 4, h = g & 15;
        const void* wsel = (proj == 0) ? wq : ((proj == 1) ? wk : wv);
        src = isbf ? (const void*)((const unsigned short*)wsel + (size_t)h * Cn * CAc)
                   : (const void*)((const float*)wsel + (size_t)h * Cn * CAc);
        dst = wT + (size_t)g * CAc * Cn;
        R = Cn; Cw = CAc; r0 = ct * 32; c0 = at * 32;
    } else {
        int rem = bx - 7168;
        src = wo; dst = woT;
        R = Cn; Cw = Cn;
        r0 = (rem >> 5) * 32; c0 = (rem & 31) * 32;
    }
#pragma unroll
    for (int j = 0; j < 4; j++)
        tile[ty + j * 8][tx] = ld_elem(src, (size_t)(r0 + ty + j * 8) * Cw + c0 + tx, isbf);
    __syncthreads();
#pragma unroll
    for (int j = 0; j < 4; j++)
        dst[(size_t)(c0 + ty + j * 8) * R + r0 + tx] = tile[tx][ty + j * 8];
}

// ---------------------------------------------------------------------------
// QKV GEMM 128x128, K=1024, BK=32, async dbuf staging. q is scaled by QSCALE
// (exponent+log2e fold; attention then uses raw exp2). vT epilogue goes
// through an LDS transpose (reusing the staging LDS) so the [Ca][T] stores
// are 100% coalesced 16B. BUGFIX r8->r9: t-offset in the vT store is batch-
// local (mBase & (Tc-1)), not raw mBase — raw mBase double-counted batch 1's
// +2048, shifting all of batch 1's V one a-row ahead.
// ---------------------------------------------------------------------------
__global__ __launch_bounds__(256) void gemm_qkv(
    const void* __restrict__ xin,
    const unsigned short* __restrict__ xb,
    const unsigned short* __restrict__ Bt,
    unsigned short* __restrict__ o0,
    unsigned short* __restrict__ o1,
    unsigned short* __restrict__ o2)
{
    __shared__ alignas(16) unsigned short SH[4][128 * 32];   // Al=SH[0..1], Bl=SH[2..3]
    const int tid = threadIdx.x;
    const int wave = tid >> 6, lane = tid & 63;
    const int l15 = lane & 15, quad = lane >> 4;
    const int mBase = blockIdx.y * 128, nBase = blockIdx.x * 128;
    const int mOff = (wave & 1) * 64, nOff = (wave >> 1) * 64;

    const int isbf = detect_bf16((const unsigned short*)xin);
    const unsigned short* Amat = isbf ? (const unsigned short*)xin : xb;

    const int srow = lane >> 2;                   // 16 rows x 4 chunks per inst
    const int sgc  = (lane & 3) ^ (srow & 3);     // swizzled global chunk
    const int sw = (quad ^ (l15 & 3)) * 8;        // swizzled frag chunk

    f32x4 acc[4][4];
#pragma unroll
    for (int i = 0; i < 4; i++)
#pragma unroll
        for (int j = 0; j < 4; j++)
            acc[i][j] = (f32x4){0.f, 0.f, 0.f, 0.f};

#pragma unroll
    for (int t = 0; t < 2; t++) {
        int rl = wave * 32 + t * 16;
        async_cp16(Amat + (size_t)(mBase + rl + srow) * Cn + sgc * 8, &SH[0][rl * 32]);
        async_cp16(Bt   + (size_t)(nBase + rl + srow) * Cn + sgc * 8, &SH[2][rl * 32]);
    }
    __syncthreads();

    for (int kk = 0; kk < 32; kk++) {
        const int cur = kk & 1;
        if (kk < 31) {
            const int k1 = (kk + 1) * 32;
#pragma unroll
            for (int t = 0; t < 2; t++) {
                int rl = wave * 32 + t * 16;
                async_cp16(Amat + (size_t)(mBase + rl + srow) * Cn + k1 + sgc * 8, &SH[1 - cur][rl * 32]);
                async_cp16(Bt   + (size_t)(nBase + rl + srow) * Cn + k1 + sgc * 8, &SH[3 - cur][rl * 32]);
            }
        }
        short8 af[4], bfr[4];
#pragma unroll
        for (int i = 0; i < 4; i++)
            af[i] = *(const short8*)(&SH[cur][(mOff + i * 16 + l15) * 32 + sw]);
#pragma unroll
        for (int j = 0; j < 4; j++)
            bfr[j] = *(const short8*)(&SH[2 + cur][(nOff + j * 16 + l15) * 32 + sw]);
#pragma unroll
        for (int i = 0; i < 4; i++)
#pragma unroll
            for (int j = 0; j < 4; j++)
                acc[i][j] = __builtin_amdgcn_mfma_f32_16x16x32_bf16(af[i], bfr[j], acc[i][j], 0, 0, 0);
        __syncthreads();
    }

    const int bb = mBase >> 11;                    // batch (tile never straddles)
    if (nBase < 2048) {
        // q or k: per-block uniform; q gets QSCALE
        const float sc = (nBase < 1024) ? QSCALE : 1.0f;
        unsigned short* dst = (nBase < 1024) ? o0 : o1;
#pragma unroll
        for (int i = 0; i < 4; i++) {
            int m0 = mBase + mOff + i * 16 + quad * 4;
            int t0 = m0 & (Tc - 1);
#pragma unroll
            for (int j = 0; j < 4; j++) {
                int n = nBase + nOff + j * 16 + l15;
                int h = (n >> 6) & 15, a = n & 63;
                size_t base = ((size_t)(bb * Hc + h) * Tc + t0) * CAc + a;
#pragma unroll
                for (int r = 0; r < 4; r++)
                    dst[base + (size_t)r * CAc] = f2bf(acc[i][j][r] * sc);
            }
        }
    } else {
        // v -> vT via LDS transpose (SH is dead after the K-loop; 32KB = 128x128)
        unsigned short* Cl = &SH[0][0];
#pragma unroll
        for (int i = 0; i < 4; i++) {
            int c16 = (mOff >> 3) + i * 2 + (quad >> 1);   // 16B chunk of m
            int p = quad & 1;                               // 8B half
#pragma unroll
            for (int j = 0; j < 4; j++) {
                int nl = nOff + j * 16 + l15;
                int cs = c16 ^ (nl & 7);
                uint2 v8;
                v8.x = pack_rne(acc[i][j][0], acc[i][j][1]);
                v8.y = pack_rne(acc[i][j][2], acc[i][j][3]);
                *(uint2*)(&Cl[nl * 128 + cs * 8 + p * 4]) = v8;
            }
        }
        __syncthreads();
        const int tLoc = mBase & (Tc - 1);                  // batch-local t base (THE FIX)
#pragma unroll
        for (int pp = 0; pp < 8; pp++) {
            int vr = pp * 16 + wave * 4 + (lane >> 4);      // 0..127 (= n-local)
            int cc = lane & 15;                              // 16B chunk of t
            int cs = cc ^ (vr & 7);
            uint4 val = *(const uint4*)(&Cl[vr * 128 + cs * 8]);
            int n = nBase + vr;
            int hh = (n >> 6) & 15, a = n & 63;
            *(uint4*)(&o2[((size_t)(bb * Hc + hh) * CAc + a) * Tc + tLoc + cc * 8]) = val;
        }
    }
}

// ---------------------------------------------------------------------------
// Output GEMM: 64x128 tiles (512 blocks -> 2/CU), K=1024, BK=32, async dbuf.
// Output dtype self-detected from x.
// ---------------------------------------------------------------------------
__global__ __launch_bounds__(256) void gemm_out(
    const unsigned short* __restrict__ Amat,
    const unsigned short* __restrict__ Bt,
    void* __restrict__ o0,
    const void* __restrict__ xin)
{
    __shared__ alignas(16) unsigned short Al[2][64 * 32];
    __shared__ alignas(16) unsigned short Bl[2][128 * 32];
    const int tid = threadIdx.x;
    const int wave = tid >> 6, lane = tid & 63;
    const int l15 = lane & 15, quad = lane >> 4;
    const int mBase = blockIdx.y * 64, nBase = blockIdx.x * 128;
    const int mOff = (wave & 1) * 32, nOff = (wave >> 1) * 64;

    const int isbf = detect_bf16((const unsigned short*)xin);

    const int srow = lane >> 2;
    const int sgc  = (lane & 3) ^ (srow & 3);
    const int sw = (quad ^ (l15 & 3)) * 8;

    f32x4 acc[2][4];
#pragma unroll
    for (int i = 0; i < 2; i++)
#pragma unroll
        for (int j = 0; j < 4; j++)
            acc[i][j] = (f32x4){0.f, 0.f, 0.f, 0.f};

    {
        int rlA = wave * 16;
        async_cp16(Amat + (size_t)(mBase + rlA + srow) * Cn + sgc * 8, &Al[0][rlA * 32]);
#pragma unroll
        for (int t = 0; t < 2; t++) {
            int rlB = wave * 32 + t * 16;
            async_cp16(Bt + (size_t)(nBase + rlB + srow) * Cn + sgc * 8, &Bl[0][rlB * 32]);
        }
    }
    __syncthreads();

    for (int kk = 0; kk < 32; kk++) {
        const int cur = kk & 1;
        if (kk < 31) {
            const int k1 = (kk + 1) * 32;
            int rlA = wave * 16;
            async_cp16(Amat + (size_t)(mBase + rlA + srow) * Cn + k1 + sgc * 8, &Al[1 - cur][rlA * 32]);
#pragma unroll
            for (int t = 0; t < 2; t++) {
                int rlB = wave * 32 + t * 16;
                async_cp16(Bt + (size_t)(nBase + rlB + srow) * Cn + k1 + sgc * 8, &Bl[1 - cur][rlB * 32]);
            }
        }
        short8 af[2], bfr[4];
#pragma unroll
        for (int i = 0; i < 2; i++)
            af[i] = *(const short8*)(&Al[cur][(mOff + i * 16 + l15) * 32 + sw]);
#pragma unroll
        for (int j = 0; j < 4; j++)
            bfr[j] = *(const short8*)(&Bl[cur][(nOff + j * 16 + l15) * 32 + sw]);
#pragma unroll
        for (int i = 0; i < 2; i++)
#pragma unroll
            for (int j = 0; j < 4; j++)
                acc[i][j] = __builtin_amdgcn_mfma_f32_16x16x32_bf16(af[i], bfr[j], acc[i][j], 0, 0, 0);
        __syncthreads();
    }

#pragma unroll
    for (int i = 0; i < 2; i++) {
        int m0 = mBase + mOff + i * 16 + quad * 4;
#pragma unroll
        for (int j = 0; j < 4; j++) {
            int n = nBase + nOff + j * 16 + l15;
            if (isbf) {
#pragma unroll
                for (int r = 0; r < 4; r++)
                    ((unsigned short*)o0)[(size_t)(m0 + r) * Cn + n] = f2bf(acc[i][j][r]);
            } else {
#pragma unroll
                for (int r = 0; r < 4; r++)
                    ((float*)o0)[(size_t)(m0 + r) * Cn + n] = acc[i][j][r];
            }
        }
    }
}

// ---------------------------------------------------------------------------
// Flash attention, causal, PAIRED q-tiles {pr, 31-pr} sharing one K/V stream.
// q arrives pre-scaled by 0.125*log2e -> scores feed exp2f DIRECTLY (no mul).
// P packs via single v_perm_b32 truncation. Row-sums via ones-MFMA. No
// cross-lane ops. Double-buffered swizzled global_load_lds, 1 barrier/iter.
// ---------------------------------------------------------------------------
__global__ __launch_bounds__(256) void attn_pair(
    const unsigned short* __restrict__ q,
    const unsigned short* __restrict__ k,
    const unsigned short* __restrict__ vT,
    unsigned short* __restrict__ y)
{
    __shared__ alignas(16) unsigned short Kl[2][64 * 64];
    __shared__ alignas(16) unsigned short Vl[2][64 * 64];
    const int LDP = 72;
    __shared__ alignas(16) unsigned short Pl[4][16 * LDP];
    const int bx = blockIdx.x;
    const int pr = bx & 15, bh = bx >> 4;
    const int h = bh & 15, b = bh >> 4;
    const int qt1 = pr, qt2 = 31 - pr;
    const int tid = threadIdx.x;
    const int wave = tid >> 6, lane = tid & 63;
    const int l15 = lane & 15, quad = lane >> 4;
    const int m0w1 = qt1 * 64 + wave * 16;
    const int m0w2 = qt2 * 64 + wave * 16;
    const size_t bhoff = (size_t)(b * Hc + h);
    const unsigned short* qh = q + bhoff * Tc * CAc;
    const unsigned short* kh = k + bhoff * Tc * CAc;
    const unsigned short* vh = vT + bhoff * CAc * Tc;

    const int srow = (lane >> 3);
    const int sgc  = (lane & 7) ^ srow;
    const int h7 = l15 & 7;
    const int sw0 = ((quad ^ h7) << 3);
    const int sw1 = (((4 + quad) ^ h7) << 3);

    short8 qf1[2], qf2[2];
#pragma unroll
    for (int s = 0; s < 2; s++) {
        qf1[s] = *(const short8*)(&qh[(size_t)(m0w1 + l15) * CAc + s * 32 + quad * 8]);
        qf2[s] = *(const short8*)(&qh[(size_t)(m0w2 + l15) * CAc + s * 32 + quad * 8]);
    }

    f32x4 oacc1[4], oacc2[4], osum1, osum2;
#pragma unroll
    for (int j2 = 0; j2 < 4; j2++) {
        oacc1[j2] = (f32x4){0.f, 0.f, 0.f, 0.f};
        oacc2[j2] = (f32x4){0.f, 0.f, 0.f, 0.f};
    }
    osum1 = (f32x4){0.f, 0.f, 0.f, 0.f};
    osum2 = (f32x4){0.f, 0.f, 0.f, 0.f};

    const unsigned short ONE = 0x3F80;
    short8 ones;
#pragma unroll
    for (int i = 0; i < 8; i++) ones[i] = (short)ONE;

    unsigned short* Pw = &Pl[wave][0];

#pragma unroll
    for (int t = 0; t < 2; t++) {
        int rl = wave * 16 + t * 8;
        async_cp16(kh + (size_t)(rl + srow) * CAc + sgc * 8, &Kl[0][rl * 64]);
        async_cp16(vh + (size_t)(rl + srow) * Tc  + sgc * 8, &Vl[0][rl * 64]);
    }
    __syncthreads();

    for (int kt = 0; kt <= qt2; kt++) {
        const int k0 = kt * 64;
        const int cur = kt & 1;
        const bool act1 = (kt <= qt1);
        if (kt < qt2) {
            const unsigned short* kg = kh + (size_t)(k0 + 64) * CAc;
            const unsigned short* vg = vh + (k0 + 64);
#pragma unroll
            for (int t = 0; t < 2; t++) {
                int rl = wave * 16 + t * 8;
                async_cp16(kg + (size_t)(rl + srow) * CAc + sgc * 8, &Kl[1 - cur][rl * 64]);
                async_cp16(vg + (size_t)(rl + srow) * Tc  + sgc * 8, &Vl[1 - cur][rl * 64]);
            }
        }
        const unsigned short* Kc = Kl[cur];
        const unsigned short* Vc = Vl[cur];

        float s1[4][4], s2[4][4];
#pragma unroll
        for (int j = 0; j < 4; j++) {
            short8 kf0 = *(const short8*)(&Kc[(j * 16 + l15) * 64 + sw0]);
            short8 kf1 = *(const short8*)(&Kc[(j * 16 + l15) * 64 + sw1]);
            f32x4 z2 = (f32x4){0.f, 0.f, 0.f, 0.f};
            z2 = __builtin_amdgcn_mfma_f32_16x16x32_bf16(kf0, qf2[0], z2, 0, 0, 0);
            z2 = __builtin_amdgcn_mfma_f32_16x16x32_bf16(kf1, qf2[1], z2, 0, 0, 0);
#pragma unroll
            for (int r = 0; r < 4; r++) s2[j][r] = z2[r];
            if (act1) {
                f32x4 z1 = (f32x4){0.f, 0.f, 0.f, 0.f};
                z1 = __builtin_amdgcn_mfma_f32_16x16x32_bf16(kf0, qf1[0], z1, 0, 0, 0);
                z1 = __builtin_amdgcn_mfma_f32_16x16x32_bf16(kf1, qf1[1], z1, 0, 0, 0);
#pragma unroll
                for (int r = 0; r < 4; r++) s1[j][r] = z1[r];
            }
        }

        // exp2 directly (scale pre-folded into q); mask only on diagonal
        if (kt == qt2) {
            int tg = m0w2 + l15;
#pragma unroll
            for (int j = 0; j < 4; j++)
#pragma unroll
                for (int r = 0; r < 4; r++) {
                    int sg = k0 + j * 16 + quad * 4 + r;
                    s2[j][r] = (sg <= tg) ? exp2f(s2[j][r]) : 0.f;
                }
        } else {
#pragma unroll
            for (int j = 0; j < 4; j++)
#pragma unroll
                for (int r = 0; r < 4; r++)
                    s2[j][r] = exp2f(s2[j][r]);
        }
        if (act1) {
            if (kt == qt1) {
                int tg = m0w1 + l15;
#pragma unroll
                for (int j = 0; j < 4; j++)
#pragma unroll
                    for (int r = 0; r < 4; r++) {
                        int sg = k0 + j * 16 + quad * 4 + r;
                        s1[j][r] = (sg <= tg) ? exp2f(s1[j][r]) : 0.f;
                    }
            } else {
#pragma unroll
                for (int j = 0; j < 4; j++)
#pragma unroll
                    for (int r = 0; r < 4; r++)
                        s1[j][r] = exp2f(s1[j][r]);
            }
        }

        short8 pa2[2], pa1[2];
#pragma unroll
        for (int j = 0; j < 4; j++) {
            uint2 v;
            v.x = pack_trunc(s2[j][0], s2[j][1]);
            v.y = pack_trunc(s2[j][2], s2[j][3]);
            *(uint2*)(&Pw[l15 * LDP + j * 16 + quad * 4]) = v;
        }
#pragma unroll
        for (int c = 0; c < 2; c++)
            pa2[c] = *(const short8*)(&Pw[l15 * LDP + c * 32 + quad * 8]);
        if (act1) {
#pragma unroll
            for (int j = 0; j < 4; j++) {
                uint2 v;
                v.x = pack_trunc(s1[j][0], s1[j][1]);
                v.y = pack_trunc(s1[j][2], s1[j][3]);
                *(uint2*)(&Pw[l15 * LDP + j * 16 + quad * 4]) = v;
            }
#pragma unroll
            for (int c = 0; c < 2; c++)
                pa1[c] = *(const short8*)(&Pw[l15 * LDP + c * 32 + quad * 8]);
        }

#pragma unroll
        for (int c = 0; c < 2; c++) {
#pragma unroll
            for (int j2 = 0; j2 < 4; j2++) {
                short8 vb = *(const short8*)(&Vc[(j2 * 16 + l15) * 64 + (c ? sw1 : sw0)]);
                oacc2[j2] = __builtin_amdgcn_mfma_f32_16x16x32_bf16(pa2[c], vb, oacc2[j2], 0, 0, 0);
                if (act1)
                    oacc1[j2] = __builtin_amdgcn_mfma_f32_16x16x32_bf16(pa1[c], vb, oacc1[j2], 0, 0, 0);
            }
            osum2 = __builtin_amdgcn_mfma_f32_16x16x32_bf16(pa2[c], ones, osum2, 0, 0, 0);
            if (act1)
                osum1 = __builtin_amdgcn_mfma_f32_16x16x32_bf16(pa1[c], ones, osum1, 0, 0, 0);
        }
        __syncthreads();
    }

    float ri1[4], ri2[4];
#pragma unroll
    for (int r = 0; r < 4; r++) { ri1[r] = 1.0f / osum1[r]; ri2[r] = 1.0f / osum2[r]; }
#pragma unroll
    for (int j2 = 0; j2 < 4; j2++) {
#pragma unroll
        for (int r = 0; r < 4; r++) {
            int t1 = m0w1 + quad * 4 + r;
            int t2 = m0w2 + quad * 4 + r;
            y[((size_t)b * Tc + t1) * Cn + h * CAc + j2 * 16 + l15] = f2bf(oacc1[j2][r] * ri1[r]);
            y[((size_t)b * Tc + t2) * Cn + h * CAc + j2 * 16 + l15] = f2bf(oacc2[j2][r] * ri2[r]);
        }
    }
}

// ---------------------------------------------------------------------------
extern "C" void kernel_launch(void* const* d_in, const int* in_sizes, int n_in,
                              void* d_out, int out_size, void* d_ws, size_t ws_size,
                              hipStream_t stream) {
    const void* x  = d_in[0];
    const void* wq = d_in[1];
    const void* wk = d_in[2];
    const void* wv = d_in[3];
    const void* wo = d_in[4];
    char* ws = (char*)d_ws;
    // ws layout (MB): wT@1(6) | woT@7(2) | xb@9(8) | q@17(8) | k@25(8) | vT@33(8) | y@41(8)
    unsigned short* wT  = (unsigned short*)(ws + ((size_t)1 << 20));
    unsigned short* woT = (unsigned short*)(ws + ((size_t)7 << 20));
    unsigned short* xb  = (unsigned short*)(ws + ((size_t)9 << 20));
    unsigned short* qb  = (unsigned short*)(ws + ((size_t)17 << 20));
    unsigned short* kb  = (unsigned short*)(ws + ((size_t)25 << 20));
    unsigned short* vTb = (unsigned short*)(ws + ((size_t)33 << 20));
    unsigned short* yb  = (unsigned short*)(ws + ((size_t)41 << 20));

    prep<<<dim3(8192), dim3(256), 0, stream>>>(x, xb, wq, wk, wv, wo, wT, woT);
    gemm_qkv<<<dim3(24, 32), dim3(256), 0, stream>>>(x, xb, wT, qb, kb, vTb);
    attn_pair<<<dim3(512), dim3(256), 0, stream>>>(qb, kb, vTb, yb);
    gemm_out<<<dim3(8, 64), dim3(256), 0, stream>>>(yb, woT, d_out, x);
}

// Round 10
// 185.267 us; speedup vs baseline: 1.1150x; 1.1150x over previous
//
#include <hip/hip_runtime.h>
#include <stdint.h>

#define Bc 2
#define Tc 2048
#define Cn 1024
#define Hc 16
#define CAc 64

typedef __attribute__((ext_vector_type(8))) short short8;
typedef __attribute__((ext_vector_type(4))) float f32x4;

// 0.125 (1/sqrt(64)) * log2(e): folded into q so attention uses raw v_exp_f32.
#define QSCALE 0.18033688011112042f

__device__ __forceinline__ unsigned short f2bf(float f) {
    unsigned int u = __builtin_bit_cast(unsigned int, f);
    return (unsigned short)((u + 0x7fffu + ((u >> 16) & 1u)) >> 16);
}
__device__ __forceinline__ unsigned int pack_rne(float a, float b) {
    return (unsigned int)f2bf(a) | ((unsigned int)f2bf(b) << 16);
}
// truncating bf16x2 pack in ONE v_perm_b32 (bias cancels in the P/sum ratio)
__device__ __forceinline__ unsigned int pack_trunc(float a, float b) {
    return __builtin_amdgcn_perm(__builtin_bit_cast(unsigned int, b),
                                 __builtin_bit_cast(unsigned int, a), 0x07060302u);
}

// async global->LDS, 16B per lane; HW scatters lane i to lds_base + i*16
__device__ __forceinline__ void async_cp16(const unsigned short* g, unsigned short* l) {
    __builtin_amdgcn_global_load_lds(
        (const __attribute__((address_space(1))) unsigned int*)g,
        (__attribute__((address_space(3))) unsigned int*)l,
        16, 0, 0);
}

// Self-detect input dtype from x. 1 -> bf16, 0 -> f32. Uniform across blocks.
__device__ __forceinline__ int detect_bf16(const unsigned short* x) {
    int c = 0;
#pragma unroll
    for (int i = 0; i < 64; i++) {
        unsigned short u = x[i * 2];           // even indices: f32 mantissa halves
        int e = (u >> 7) & 0xFF;
        c += (e >= 0x68 && e <= 0x90);
    }
    return c > 32;
}

__device__ __forceinline__ unsigned short ld_elem(const void* base, size_t off, int isbf) {
    return isbf ? ((const unsigned short*)base)[off] : f2bf(((const float*)base)[off]);
}

// ---------------------------------------------------------------------------
// prep: blocks [0,4096): convert x -> xb (skipped when x is bf16).
// [4096,7168): transpose w_q/w_k/w_v. [7168,8192): transpose w_o.
// ---------------------------------------------------------------------------
__global__ __launch_bounds__(256) void prep(
    const void* __restrict__ xin, unsigned short* __restrict__ xb,
    const void* __restrict__ wq, const void* __restrict__ wk,
    const void* __restrict__ wv, const void* __restrict__ wo,
    unsigned short* __restrict__ wT, unsigned short* __restrict__ woT)
{
    const int isbf = detect_bf16((const unsigned short*)xin);
    const int bx = blockIdx.x;
    if (bx < 4096) {
        if (isbf) return;
        int idx = (bx * 256 + threadIdx.x) * 4;
        const float* xf = (const float*)xin;
        float4 v = *(const float4*)(xf + idx);
        uint2 p;
        p.x = pack_rne(v.x, v.y);
        p.y = pack_rne(v.z, v.w);
        *(uint2*)(&xb[idx]) = p;
        return;
    }
    __shared__ unsigned short tile[32][33];
    const int t = threadIdx.x;
    const int tx = t & 31, ty = t >> 5;
    const void* src;
    unsigned short* dst;
    int R, Cw, r0, c0;
    if (bx < 7168) {
        int rem0 = bx - 4096;
        int g = rem0 >> 6;            // proj*16 + h
        int rem = rem0 & 63;
        int ct = rem >> 1;
        int at = rem & 1;
        int proj = g >> 4, h = g & 15;
        const void* wsel = (proj == 0) ? wq : ((proj == 1) ? wk : wv);
        src = isbf ? (const void*)((const unsigned short*)wsel + (size_t)h * Cn * CAc)
                   : (const void*)((const float*)wsel + (size_t)h * Cn * CAc);
        dst = wT + (size_t)g * CAc * Cn;
        R = Cn; Cw = CAc; r0 = ct * 32; c0 = at * 32;
    } else {
        int rem = bx - 7168;
        src = wo; dst = woT;
        R = Cn; Cw = Cn;
        r0 = (rem >> 5) * 32; c0 = (rem & 31) * 32;
    }
#pragma unroll
    for (int j = 0; j < 4; j++)
        tile[ty + j * 8][tx] = ld_elem(src, (size_t)(r0 + ty + j * 8) * Cw + c0 + tx, isbf);
    __syncthreads();
#pragma unroll
    for (int j = 0; j < 4; j++)
        dst[(size_t)(c0 + ty + j * 8) * R + r0 + tx] = tile[tx][ty + j * 8];
}

// ---------------------------------------------------------------------------
// QKV GEMM 128x128, K=1024, BK=32, async dbuf staging. q scaled by QSCALE.
// vT epilogue via LDS transpose (coalesced 16B stores; t-offset batch-local).
// ---------------------------------------------------------------------------
__global__ __launch_bounds__(256) void gemm_qkv(
    const void* __restrict__ xin,
    const unsigned short* __restrict__ xb,
    const unsigned short* __restrict__ Bt,
    unsigned short* __restrict__ o0,
    unsigned short* __restrict__ o1,
    unsigned short* __restrict__ o2)
{
    __shared__ alignas(16) unsigned short SH[4][128 * 32];   // Al=SH[0..1], Bl=SH[2..3]
    const int tid = threadIdx.x;
    const int wave = tid >> 6, lane = tid & 63;
    const int l15 = lane & 15, quad = lane >> 4;
    const int mBase = blockIdx.y * 128, nBase = blockIdx.x * 128;
    const int mOff = (wave & 1) * 64, nOff = (wave >> 1) * 64;

    const int isbf = detect_bf16((const unsigned short*)xin);
    const unsigned short* Amat = isbf ? (const unsigned short*)xin : xb;

    const int srow = lane >> 2;
    const int sgc  = (lane & 3) ^ (srow & 3);
    const int sw = (quad ^ (l15 & 3)) * 8;

    f32x4 acc[4][4];
#pragma unroll
    for (int i = 0; i < 4; i++)
#pragma unroll
        for (int j = 0; j < 4; j++)
            acc[i][j] = (f32x4){0.f, 0.f, 0.f, 0.f};

#pragma unroll
    for (int t = 0; t < 2; t++) {
        int rl = wave * 32 + t * 16;
        async_cp16(Amat + (size_t)(mBase + rl + srow) * Cn + sgc * 8, &SH[0][rl * 32]);
        async_cp16(Bt   + (size_t)(nBase + rl + srow) * Cn + sgc * 8, &SH[2][rl * 32]);
    }
    __syncthreads();

    for (int kk = 0; kk < 32; kk++) {
        const int cur = kk & 1;
        if (kk < 31) {
            const int k1 = (kk + 1) * 32;
#pragma unroll
            for (int t = 0; t < 2; t++) {
                int rl = wave * 32 + t * 16;
                async_cp16(Amat + (size_t)(mBase + rl + srow) * Cn + k1 + sgc * 8, &SH[1 - cur][rl * 32]);
                async_cp16(Bt   + (size_t)(nBase + rl + srow) * Cn + k1 + sgc * 8, &SH[3 - cur][rl * 32]);
            }
        }
        short8 af[4], bfr[4];
#pragma unroll
        for (int i = 0; i < 4; i++)
            af[i] = *(const short8*)(&SH[cur][(mOff + i * 16 + l15) * 32 + sw]);
#pragma unroll
        for (int j = 0; j < 4; j++)
            bfr[j] = *(const short8*)(&SH[2 + cur][(nOff + j * 16 + l15) * 32 + sw]);
#pragma unroll
        for (int i = 0; i < 4; i++)
#pragma unroll
            for (int j = 0; j < 4; j++)
                acc[i][j] = __builtin_amdgcn_mfma_f32_16x16x32_bf16(af[i], bfr[j], acc[i][j], 0, 0, 0);
        __syncthreads();
    }

    const int bb = mBase >> 11;
    if (nBase < 2048) {
        const float sc = (nBase < 1024) ? QSCALE : 1.0f;
        unsigned short* dst = (nBase < 1024) ? o0 : o1;
#pragma unroll
        for (int i = 0; i < 4; i++) {
            int m0 = mBase + mOff + i * 16 + quad * 4;
            int t0 = m0 & (Tc - 1);
#pragma unroll
            for (int j = 0; j < 4; j++) {
                int n = nBase + nOff + j * 16 + l15;
                int h = (n >> 6) & 15, a = n & 63;
                size_t base = ((size_t)(bb * Hc + h) * Tc + t0) * CAc + a;
#pragma unroll
                for (int r = 0; r < 4; r++)
                    dst[base + (size_t)r * CAc] = f2bf(acc[i][j][r] * sc);
            }
        }
    } else {
        unsigned short* Cl = &SH[0][0];
#pragma unroll
        for (int i = 0; i < 4; i++) {
            int c16 = (mOff >> 3) + i * 2 + (quad >> 1);
            int p = quad & 1;
#pragma unroll
            for (int j = 0; j < 4; j++) {
                int nl = nOff + j * 16 + l15;
                int cs = c16 ^ (nl & 7);
                uint2 v8;
                v8.x = pack_rne(acc[i][j][0], acc[i][j][1]);
                v8.y = pack_rne(acc[i][j][2], acc[i][j][3]);
                *(uint2*)(&Cl[nl * 128 + cs * 8 + p * 4]) = v8;
            }
        }
        __syncthreads();
        const int tLoc = mBase & (Tc - 1);
#pragma unroll
        for (int pp = 0; pp < 8; pp++) {
            int vr = pp * 16 + wave * 4 + (lane >> 4);
            int cc = lane & 15;
            int cs = cc ^ (vr & 7);
            uint4 val = *(const uint4*)(&Cl[vr * 128 + cs * 8]);
            int n = nBase + vr;
            int hh = (n >> 6) & 15, a = n & 63;
            *(uint4*)(&o2[((size_t)(bb * Hc + hh) * CAc + a) * Tc + tLoc + cc * 8]) = val;
        }
    }
}

// ---------------------------------------------------------------------------
// Output GEMM: 64x128 tiles (512 blocks -> 2/CU), K=1024, BK=32, async dbuf.
// ---------------------------------------------------------------------------
__global__ __launch_bounds__(256) void gemm_out(
    const unsigned short* __restrict__ Amat,
    const unsigned short* __restrict__ Bt,
    void* __restrict__ o0,
    const void* __restrict__ xin)
{
    __shared__ alignas(16) unsigned short Al[2][64 * 32];
    __shared__ alignas(16) unsigned short Bl[2][128 * 32];
    const int tid = threadIdx.x;
    const int wave = tid >> 6, lane = tid & 63;
    const int l15 = lane & 15, quad = lane >> 4;
    const int mBase = blockIdx.y * 64, nBase = blockIdx.x * 128;
    const int mOff = (wave & 1) * 32, nOff = (wave >> 1) * 64;

    const int isbf = detect_bf16((const unsigned short*)xin);

    const int srow = lane >> 2;
    const int sgc  = (lane & 3) ^ (srow & 3);
    const int sw = (quad ^ (l15 & 3)) * 8;

    f32x4 acc[2][4];
#pragma unroll
    for (int i = 0; i < 2; i++)
#pragma unroll
        for (int j = 0; j < 4; j++)
            acc[i][j] = (f32x4){0.f, 0.f, 0.f, 0.f};

    {
        int rlA = wave * 16;
        async_cp16(Amat + (size_t)(mBase + rlA + srow) * Cn + sgc * 8, &Al[0][rlA * 32]);
#pragma unroll
        for (int t = 0; t < 2; t++) {
            int rlB = wave * 32 + t * 16;
            async_cp16(Bt + (size_t)(nBase + rlB + srow) * Cn + sgc * 8, &Bl[0][rlB * 32]);
        }
    }
    __syncthreads();

    for (int kk = 0; kk < 32; kk++) {
        const int cur = kk & 1;
        if (kk < 31) {
            const int k1 = (kk + 1) * 32;
            int rlA = wave * 16;
            async_cp16(Amat + (size_t)(mBase + rlA + srow) * Cn + k1 + sgc * 8, &Al[1 - cur][rlA * 32]);
#pragma unroll
            for (int t = 0; t < 2; t++) {
                int rlB = wave * 32 + t * 16;
                async_cp16(Bt + (size_t)(nBase + rlB + srow) * Cn + k1 + sgc * 8, &Bl[1 - cur][rlB * 32]);
            }
        }
        short8 af[2], bfr[4];
#pragma unroll
        for (int i = 0; i < 2; i++)
            af[i] = *(const short8*)(&Al[cur][(mOff + i * 16 + l15) * 32 + sw]);
#pragma unroll
        for (int j = 0; j < 4; j++)
            bfr[j] = *(const short8*)(&Bl[cur][(nOff + j * 16 + l15) * 32 + sw]);
#pragma unroll
        for (int i = 0; i < 2; i++)
#pragma unroll
            for (int j = 0; j < 4; j++)
                acc[i][j] = __builtin_amdgcn_mfma_f32_16x16x32_bf16(af[i], bfr[j], acc[i][j], 0, 0, 0);
        __syncthreads();
    }

#pragma unroll
    for (int i = 0; i < 2; i++) {
        int m0 = mBase + mOff + i * 16 + quad * 4;
#pragma unroll
        for (int j = 0; j < 4; j++) {
            int n = nBase + nOff + j * 16 + l15;
            if (isbf) {
#pragma unroll
                for (int r = 0; r < 4; r++)
                    ((unsigned short*)o0)[(size_t)(m0 + r) * Cn + n] = f2bf(acc[i][j][r]);
            } else {
#pragma unroll
                for (int r = 0; r < 4; r++)
                    ((float*)o0)[(size_t)(m0 + r) * Cn + n] = acc[i][j][r];
            }
        }
    }
}

// ---------------------------------------------------------------------------
// Flash attention, causal, UNPAIRED: one 64-row q-tile per block, grid 1024
// (= 4 blocks/CU; was 512 = the occupancy cap). Heavy-first dispatch:
// qt = 31-(bx>>5), bh inner — all diagonal-heavy tiles launch across CUs
// first; 4-deep co-residency balances the tail. LDS = exactly 40960 B
// (160KB/4): P buffer un-padded (16x64/wave) with pair-preserving chunk4
// XOR swizzle instead of +8 padding. exp2 via __builtin_amdgcn_exp2f
// (raw v_exp_f32 — exp2f's non-fast-math lowering added fixup VALU).
// ---------------------------------------------------------------------------
__global__ __launch_bounds__(256, 4) void attn_t(
    const unsigned short* __restrict__ q,
    const unsigned short* __restrict__ k,
    const unsigned short* __restrict__ vT,
    unsigned short* __restrict__ y)
{
    __shared__ alignas(16) unsigned short Kl[2][64 * 64];   // 16 KB
    __shared__ alignas(16) unsigned short Vl[2][64 * 64];   // 16 KB
    __shared__ alignas(16) unsigned short Pl[4][16 * 64];   // 8 KB  -> total 40960
    const int bx = blockIdx.x;
    const int qt = 31 - (bx >> 5);                // heavy tiles first
    const int bh = bx & 31;
    const int h = bh & 15, b = bh >> 4;
    const int tid = threadIdx.x;
    const int wave = tid >> 6, lane = tid & 63;
    const int l15 = lane & 15, quad = lane >> 4;
    const int m0w = qt * 64 + wave * 16;
    const size_t bhoff = (size_t)(b * Hc + h);
    const unsigned short* qh = q + bhoff * Tc * CAc;
    const unsigned short* kh = k + bhoff * Tc * CAc;
    const unsigned short* vh = vT + bhoff * CAc * Tc;

    const int srow = (lane >> 3);
    const int sgc  = (lane & 7) ^ srow;           // swizzled global chunk (staging)
    const int h7 = l15 & 7;
    const int sw0 = ((quad ^ h7) << 3);           // K/V frag chunk, s=0
    const int sw1 = (((4 + quad) ^ h7) << 3);     // s=1
    // P-buffer swizzle: chunk4 write index and chunk8 read index
    const int pw_m = 2 * h7;                      // even XOR -> b128-read pairs intact

    short8 qf[2];
#pragma unroll
    for (int s = 0; s < 2; s++)
        qf[s] = *(const short8*)(&qh[(size_t)(m0w + l15) * CAc + s * 32 + quad * 8]);

    f32x4 oacc[4], osum;
#pragma unroll
    for (int j2 = 0; j2 < 4; j2++) oacc[j2] = (f32x4){0.f, 0.f, 0.f, 0.f};
    osum = (f32x4){0.f, 0.f, 0.f, 0.f};

    const unsigned short ONE = 0x3F80;
    short8 ones;
#pragma unroll
    for (int i = 0; i < 8; i++) ones[i] = (short)ONE;

    unsigned short* Pw = &Pl[wave][0];

#pragma unroll
    for (int t = 0; t < 2; t++) {
        int rl = wave * 16 + t * 8;
        async_cp16(kh + (size_t)(rl + srow) * CAc + sgc * 8, &Kl[0][rl * 64]);
        async_cp16(vh + (size_t)(rl + srow) * Tc  + sgc * 8, &Vl[0][rl * 64]);
    }
    __syncthreads();

    for (int kt = 0; kt <= qt; kt++) {
        const int k0 = kt * 64;
        const int cur = kt & 1;
        if (kt < qt) {
            const unsigned short* kg = kh + (size_t)(k0 + 64) * CAc;
            const unsigned short* vg = vh + (k0 + 64);
#pragma unroll
            for (int t = 0; t < 2; t++) {
                int rl = wave * 16 + t * 8;
                async_cp16(kg + (size_t)(rl + srow) * CAc + sgc * 8, &Kl[1 - cur][rl * 64]);
                async_cp16(vg + (size_t)(rl + srow) * Tc  + sgc * 8, &Vl[1 - cur][rl * 64]);
            }
        }
        const unsigned short* Kc = Kl[cur];
        const unsigned short* Vc = Vl[cur];

        // S^T = K Q^T: lane(quad,l15) reg r -> s = k0+j*16+quad*4+r, t = m0w+l15
        float sv[4][4];
#pragma unroll
        for (int j = 0; j < 4; j++) {
            short8 kf0 = *(const short8*)(&Kc[(j * 16 + l15) * 64 + sw0]);
            short8 kf1 = *(const short8*)(&Kc[(j * 16 + l15) * 64 + sw1]);
            f32x4 z = (f32x4){0.f, 0.f, 0.f, 0.f};
            z = __builtin_amdgcn_mfma_f32_16x16x32_bf16(kf0, qf[0], z, 0, 0, 0);
            z = __builtin_amdgcn_mfma_f32_16x16x32_bf16(kf1, qf[1], z, 0, 0, 0);
#pragma unroll
            for (int r = 0; r < 4; r++) sv[j][r] = z[r];
        }

        // exp2 (scale pre-folded into q); mask only on the diagonal tile
        if (kt == qt) {
            int tg = m0w + l15;
#pragma unroll
            for (int j = 0; j < 4; j++)
#pragma unroll
                for (int r = 0; r < 4; r++) {
                    int sg = k0 + j * 16 + quad * 4 + r;
                    sv[j][r] = (sg <= tg) ? __builtin_amdgcn_exp2f(sv[j][r]) : 0.f;
                }
        } else {
#pragma unroll
            for (int j = 0; j < 4; j++)
#pragma unroll
                for (int r = 0; r < 4; r++)
                    sv[j][r] = __builtin_amdgcn_exp2f(sv[j][r]);
        }

        // P: pack 4 consecutive-s -> b64 LDS write (chunk4-swizzled), read b128
        short8 pa[2];
#pragma unroll
        for (int j = 0; j < 4; j++) {
            uint2 v;
            v.x = pack_trunc(sv[j][0], sv[j][1]);
            v.y = pack_trunc(sv[j][2], sv[j][3]);
            *(uint2*)(&Pw[l15 * 64 + ((j * 4 + quad) ^ pw_m) * 4]) = v;
        }
#pragma unroll
        for (int c = 0; c < 2; c++)
            pa[c] = *(const short8*)(&Pw[l15 * 64 + ((c * 4 + quad) ^ h7) * 8]);

#pragma unroll
        for (int c = 0; c < 2; c++) {
#pragma unroll
            for (int j2 = 0; j2 < 4; j2++) {
                short8 vb = *(const short8*)(&Vc[(j2 * 16 + l15) * 64 + (c ? sw1 : sw0)]);
                oacc[j2] = __builtin_amdgcn_mfma_f32_16x16x32_bf16(pa[c], vb, oacc[j2], 0, 0, 0);
            }
            osum = __builtin_amdgcn_mfma_f32_16x16x32_bf16(pa[c], ones, osum, 0, 0, 0);
        }
        __syncthreads();
    }

    float ri[4];
#pragma unroll
    for (int r = 0; r < 4; r++) ri[r] = 1.0f / osum[r];
#pragma unroll
    for (int j2 = 0; j2 < 4; j2++) {
#pragma unroll
        for (int r = 0; r < 4; r++) {
            int t = m0w + quad * 4 + r;
            y[((size_t)b * Tc + t) * Cn + h * CAc + j2 * 16 + l15] = f2bf(oacc[j2][r] * ri[r]);
        }
    }
}

// ---------------------------------------------------------------------------
extern "C" void kernel_launch(void* const* d_in, const int* in_sizes, int n_in,
                              void* d_out, int out_size, void* d_ws, size_t ws_size,
                              hipStream_t stream) {
    const void* x  = d_in[0];
    const void* wq = d_in[1];
    const void* wk = d_in[2];
    const void* wv = d_in[3];
    const void* wo = d_in[4];
    char* ws = (char*)d_ws;
    // ws layout (MB): wT@1(6) | woT@7(2) | xb@9(8) | q@17(8) | k@25(8) | vT@33(8) | y@41(8)
    unsigned short* wT  = (unsigned short*)(ws + ((size_t)1 << 20));
    unsigned short* woT = (unsigned short*)(ws + ((size_t)7 << 20));
    unsigned short* xb  = (unsigned short*)(ws + ((size_t)9 << 20));
    unsigned short* qb  = (unsigned short*)(ws + ((size_t)17 << 20));
    unsigned short* kb  = (unsigned short*)(ws + ((size_t)25 << 20));
    unsigned short* vTb = (unsigned short*)(ws + ((size_t)33 << 20));
    unsigned short* yb  = (unsigned short*)(ws + ((size_t)41 << 20));

    prep<<<dim3(8192), dim3(256), 0, stream>>>(x, xb, wq, wk, wv, wo, wT, woT);
    gemm_qkv<<<dim3(24, 32), dim3(256), 0, stream>>>(x, xb, wT, qb, kb, vTb);
    attn_t<<<dim3(1024), dim3(256), 0, stream>>>(qb, kb, vTb, yb);
    gemm_out<<<dim3(8, 64), dim3(256), 0, stream>>>(yb, woT, d_out, x);
}

// Round 11
// 184.044 us; speedup vs baseline: 1.1224x; 1.0066x over previous
//
#include <hip/hip_runtime.h>
#include <stdint.h>

#define Bc 2
#define Tc 2048
#define Cn 1024
#define Hc 16
#define CAc 64

typedef __attribute__((ext_vector_type(8))) short short8;
typedef __attribute__((ext_vector_type(4))) float f32x4;

// 0.125 (1/sqrt(64)) * log2(e): folded into q so attention uses raw v_exp_f32.
#define QSCALE 0.18033688011112042f

__device__ __forceinline__ unsigned short f2bf(float f) {
    unsigned int u = __builtin_bit_cast(unsigned int, f);
    return (unsigned short)((u + 0x7fffu + ((u >> 16) & 1u)) >> 16);
}
__device__ __forceinline__ unsigned int pack_rne(float a, float b) {
    return (unsigned int)f2bf(a) | ((unsigned int)f2bf(b) << 16);
}
// truncating bf16x2 pack in ONE v_perm_b32 (bias cancels in the P/sum ratio)
__device__ __forceinline__ unsigned int pack_trunc(float a, float b) {
    return __builtin_amdgcn_perm(__builtin_bit_cast(unsigned int, b),
                                 __builtin_bit_cast(unsigned int, a), 0x07060302u);
}

// async global->LDS, 16B per lane; HW scatters lane i to lds_base + i*16
__device__ __forceinline__ void async_cp16(const unsigned short* g, unsigned short* l) {
    __builtin_amdgcn_global_load_lds(
        (const __attribute__((address_space(1))) unsigned int*)g,
        (__attribute__((address_space(3))) unsigned int*)l,
        16, 0, 0);
}

// Self-detect input dtype from x. 1 -> bf16, 0 -> f32. Uniform across blocks.
__device__ __forceinline__ int detect_bf16(const unsigned short* x) {
    int c = 0;
#pragma unroll
    for (int i = 0; i < 64; i++) {
        unsigned short u = x[i * 2];           // even indices: f32 mantissa halves
        int e = (u >> 7) & 0xFF;
        c += (e >= 0x68 && e <= 0x90);
    }
    return c > 32;
}

__device__ __forceinline__ unsigned short ld_elem(const void* base, size_t off, int isbf) {
    return isbf ? ((const unsigned short*)base)[off] : f2bf(((const float*)base)[off]);
}

// ---------------------------------------------------------------------------
// prep: blocks [0,4096): convert x -> xb (skipped when x is bf16).
// [4096,7168): transpose w_q/w_k/w_v. [7168,8192): transpose w_o.
// ---------------------------------------------------------------------------
__global__ __launch_bounds__(256) void prep(
    const void* __restrict__ xin, unsigned short* __restrict__ xb,
    const void* __restrict__ wq, const void* __restrict__ wk,
    const void* __restrict__ wv, const void* __restrict__ wo,
    unsigned short* __restrict__ wT, unsigned short* __restrict__ woT)
{
    const int isbf = detect_bf16((const unsigned short*)xin);
    const int bx = blockIdx.x;
    if (bx < 4096) {
        if (isbf) return;
        int idx = (bx * 256 + threadIdx.x) * 4;
        const float* xf = (const float*)xin;
        float4 v = *(const float4*)(xf + idx);
        uint2 p;
        p.x = pack_rne(v.x, v.y);
        p.y = pack_rne(v.z, v.w);
        *(uint2*)(&xb[idx]) = p;
        return;
    }
    __shared__ unsigned short tile[32][33];
    const int t = threadIdx.x;
    const int tx = t & 31, ty = t >> 5;
    const void* src;
    unsigned short* dst;
    int R, Cw, r0, c0;
    if (bx < 7168) {
        int rem0 = bx - 4096;
        int g = rem0 >> 6;            // proj*16 + h
        int rem = rem0 & 63;
        int ct = rem >> 1;
        int at = rem & 1;
        int proj = g >> 4, h = g & 15;
        const void* wsel = (proj == 0) ? wq : ((proj == 1) ? wk : wv);
        src = isbf ? (const void*)((const unsigned short*)wsel + (size_t)h * Cn * CAc)
                   : (const void*)((const float*)wsel + (size_t)h * Cn * CAc);
        dst = wT + (size_t)g * CAc * Cn;
        R = Cn; Cw = CAc; r0 = ct * 32; c0 = at * 32;
    } else {
        int rem = bx - 7168;
        src = wo; dst = woT;
        R = Cn; Cw = Cn;
        r0 = (rem >> 5) * 32; c0 = (rem & 31) * 32;
    }
#pragma unroll
    for (int j = 0; j < 4; j++)
        tile[ty + j * 8][tx] = ld_elem(src, (size_t)(r0 + ty + j * 8) * Cw + c0 + tx, isbf);
    __syncthreads();
#pragma unroll
    for (int j = 0; j < 4; j++)
        dst[(size_t)(c0 + ty + j * 8) * R + r0 + tx] = tile[tx][ty + j * 8];
}

// ---------------------------------------------------------------------------
// QKV GEMM 128x128 block, TWO waves (128 threads), wave tile 64x128:
// LDS bytes/MAC drops 1.33x vs 64x64 wave tiles (K-loop is ds_read_b128
// bound: 12 waves x 8KB = 750cyc/CU/iter at 64x64 -> 25% MfmaUtil measured;
// 64x128 reads 12KB per 262K MAC). K=1024, BK=32, async dbuf staging.
// q scaled by QSCALE. vT epilogue via LDS transpose (coalesced 16B stores).
// __launch_bounds__(128,2): cap VGPR at 256 so 3 blocks/CU co-reside.
// ---------------------------------------------------------------------------
__global__ __launch_bounds__(128, 2) void gemm_qkv(
    const void* __restrict__ xin,
    const unsigned short* __restrict__ xb,
    const unsigned short* __restrict__ Bt,
    unsigned short* __restrict__ o0,
    unsigned short* __restrict__ o1,
    unsigned short* __restrict__ o2)
{
    __shared__ alignas(16) unsigned short SH[4][128 * 32];   // Al=SH[0..1], Bl=SH[2..3]
    const int tid = threadIdx.x;
    const int wave = tid >> 6, lane = tid & 63;
    const int l15 = lane & 15, quad = lane >> 4;
    const int mBase = blockIdx.y * 128, nBase = blockIdx.x * 128;
    const int mOff = wave * 64;                   // wave tile: m 64, n 128

    const int isbf = detect_bf16((const unsigned short*)xin);
    const unsigned short* Amat = isbf ? (const unsigned short*)xin : xb;

    const int srow = lane >> 2;                   // 16 rows x 4 chunks per inst
    const int sgc  = (lane & 3) ^ (srow & 3);     // swizzled global chunk
    const int sw = (quad ^ (l15 & 3)) * 8;        // swizzled frag chunk

    f32x4 acc[4][8];
#pragma unroll
    for (int i = 0; i < 4; i++)
#pragma unroll
        for (int j = 0; j < 8; j++)
            acc[i][j] = (f32x4){0.f, 0.f, 0.f, 0.f};

    // stage K-step 0: wave stages its own 64 rows of A and of B (4 insts each)
#pragma unroll
    for (int t = 0; t < 4; t++) {
        int rl = wave * 64 + t * 16;
        async_cp16(Amat + (size_t)(mBase + rl + srow) * Cn + sgc * 8, &SH[0][rl * 32]);
        async_cp16(Bt   + (size_t)(nBase + rl + srow) * Cn + sgc * 8, &SH[2][rl * 32]);
    }
    __syncthreads();

    for (int kk = 0; kk < 32; kk++) {
        const int cur = kk & 1;
        if (kk < 31) {
            const int k1 = (kk + 1) * 32;
#pragma unroll
            for (int t = 0; t < 4; t++) {
                int rl = wave * 64 + t * 16;
                async_cp16(Amat + (size_t)(mBase + rl + srow) * Cn + k1 + sgc * 8, &SH[1 - cur][rl * 32]);
                async_cp16(Bt   + (size_t)(nBase + rl + srow) * Cn + k1 + sgc * 8, &SH[3 - cur][rl * 32]);
            }
        }
        short8 af[4], bfr[8];
#pragma unroll
        for (int i = 0; i < 4; i++)
            af[i] = *(const short8*)(&SH[cur][(mOff + i * 16 + l15) * 32 + sw]);
#pragma unroll
        for (int j = 0; j < 8; j++)
            bfr[j] = *(const short8*)(&SH[2 + cur][(j * 16 + l15) * 32 + sw]);
#pragma unroll
        for (int i = 0; i < 4; i++)
#pragma unroll
            for (int j = 0; j < 8; j++)
                acc[i][j] = __builtin_amdgcn_mfma_f32_16x16x32_bf16(af[i], bfr[j], acc[i][j], 0, 0, 0);
        __syncthreads();
    }

    const int bb = mBase >> 11;
    if (nBase < 2048) {
        const float sc = (nBase < 1024) ? QSCALE : 1.0f;
        unsigned short* dst = (nBase < 1024) ? o0 : o1;
#pragma unroll
        for (int i = 0; i < 4; i++) {
            int m0 = mBase + mOff + i * 16 + quad * 4;
            int t0 = m0 & (Tc - 1);
#pragma unroll
            for (int j = 0; j < 8; j++) {
                int n = nBase + j * 16 + l15;
                int h = (n >> 6) & 15, a = n & 63;
                size_t base = ((size_t)(bb * Hc + h) * Tc + t0) * CAc + a;
#pragma unroll
                for (int r = 0; r < 4; r++)
                    dst[base + (size_t)r * CAc] = f2bf(acc[i][j][r] * sc);
            }
        }
    } else {
        // v -> vT via LDS transpose (SH dead after K-loop; 32KB = 128x128)
        unsigned short* Cl = &SH[0][0];
#pragma unroll
        for (int i = 0; i < 4; i++) {
            int c16 = wave * 8 + i * 2 + (quad >> 1);      // 16B chunk of m (0..15)
            int p = quad & 1;                               // 8B half
#pragma unroll
            for (int j = 0; j < 8; j++) {
                int nl = j * 16 + l15;
                int cs = c16 ^ (nl & 7);
                uint2 v8;
                v8.x = pack_rne(acc[i][j][0], acc[i][j][1]);
                v8.y = pack_rne(acc[i][j][2], acc[i][j][3]);
                *(uint2*)(&Cl[nl * 128 + cs * 8 + p * 4]) = v8;
            }
        }
        __syncthreads();
        const int tLoc = mBase & (Tc - 1);                  // batch-local t base
#pragma unroll
        for (int pp = 0; pp < 16; pp++) {
            int vr = pp * 8 + wave * 4 + (lane >> 4);       // 0..127 (= n-local)
            int cc = lane & 15;                              // 16B chunk of t
            int cs = cc ^ (vr & 7);
            uint4 val = *(const uint4*)(&Cl[vr * 128 + cs * 8]);
            int n = nBase + vr;
            int hh = (n >> 6) & 15, a = n & 63;
            *(uint4*)(&o2[((size_t)(bb * Hc + hh) * CAc + a) * Tc + tLoc + cc * 8]) = val;
        }
    }
}

// ---------------------------------------------------------------------------
// Output GEMM: 64x128 tiles (512 blocks -> 2/CU), K=1024, BK=32, async dbuf.
// ---------------------------------------------------------------------------
__global__ __launch_bounds__(256) void gemm_out(
    const unsigned short* __restrict__ Amat,
    const unsigned short* __restrict__ Bt,
    void* __restrict__ o0,
    const void* __restrict__ xin)
{
    __shared__ alignas(16) unsigned short Al[2][64 * 32];
    __shared__ alignas(16) unsigned short Bl[2][128 * 32];
    const int tid = threadIdx.x;
    const int wave = tid >> 6, lane = tid & 63;
    const int l15 = lane & 15, quad = lane >> 4;
    const int mBase = blockIdx.y * 64, nBase = blockIdx.x * 128;
    const int mOff = (wave & 1) * 32, nOff = (wave >> 1) * 64;

    const int isbf = detect_bf16((const unsigned short*)xin);

    const int srow = lane >> 2;
    const int sgc  = (lane & 3) ^ (srow & 3);
    const int sw = (quad ^ (l15 & 3)) * 8;

    f32x4 acc[2][4];
#pragma unroll
    for (int i = 0; i < 2; i++)
#pragma unroll
        for (int j = 0; j < 4; j++)
            acc[i][j] = (f32x4){0.f, 0.f, 0.f, 0.f};

    {
        int rlA = wave * 16;
        async_cp16(Amat + (size_t)(mBase + rlA + srow) * Cn + sgc * 8, &Al[0][rlA * 32]);
#pragma unroll
        for (int t = 0; t < 2; t++) {
            int rlB = wave * 32 + t * 16;
            async_cp16(Bt + (size_t)(nBase + rlB + srow) * Cn + sgc * 8, &Bl[0][rlB * 32]);
        }
    }
    __syncthreads();

    for (int kk = 0; kk < 32; kk++) {
        const int cur = kk & 1;
        if (kk < 31) {
            const int k1 = (kk + 1) * 32;
            int rlA = wave * 16;
            async_cp16(Amat + (size_t)(mBase + rlA + srow) * Cn + k1 + sgc * 8, &Al[1 - cur][rlA * 32]);
#pragma unroll
            for (int t = 0; t < 2; t++) {
                int rlB = wave * 32 + t * 16;
                async_cp16(Bt + (size_t)(nBase + rlB + srow) * Cn + k1 + sgc * 8, &Bl[1 - cur][rlB * 32]);
            }
        }
        short8 af[2], bfr[4];
#pragma unroll
        for (int i = 0; i < 2; i++)
            af[i] = *(const short8*)(&Al[cur][(mOff + i * 16 + l15) * 32 + sw]);
#pragma unroll
        for (int j = 0; j < 4; j++)
            bfr[j] = *(const short8*)(&Bl[cur][(nOff + j * 16 + l15) * 32 + sw]);
#pragma unroll
        for (int i = 0; i < 2; i++)
#pragma unroll
            for (int j = 0; j < 4; j++)
                acc[i][j] = __builtin_amdgcn_mfma_f32_16x16x32_bf16(af[i], bfr[j], acc[i][j], 0, 0, 0);
        __syncthreads();
    }

#pragma unroll
    for (int i = 0; i < 2; i++) {
        int m0 = mBase + mOff + i * 16 + quad * 4;
#pragma unroll
        for (int j = 0; j < 4; j++) {
            int n = nBase + nOff + j * 16 + l15;
            if (isbf) {
#pragma unroll
                for (int r = 0; r < 4; r++)
                    ((unsigned short*)o0)[(size_t)(m0 + r) * Cn + n] = f2bf(acc[i][j][r]);
            } else {
#pragma unroll
                for (int r = 0; r < 4; r++)
                    ((float*)o0)[(size_t)(m0 + r) * Cn + n] = acc[i][j][r];
            }
        }
    }
}

// ---------------------------------------------------------------------------
// Flash attention, causal, one 64-row q-tile per block, grid 1024 (4/CU).
// Heavy-first dispatch. LDS exactly 40960 B. exp2 via __builtin_amdgcn_exp2f.
// S^T trick; P packs via v_perm truncation; row-sums via ones-MFMA.
// ---------------------------------------------------------------------------
__global__ __launch_bounds__(256, 4) void attn_t(
    const unsigned short* __restrict__ q,
    const unsigned short* __restrict__ k,
    const unsigned short* __restrict__ vT,
    unsigned short* __restrict__ y)
{
    __shared__ alignas(16) unsigned short Kl[2][64 * 64];   // 16 KB
    __shared__ alignas(16) unsigned short Vl[2][64 * 64];   // 16 KB
    __shared__ alignas(16) unsigned short Pl[4][16 * 64];   // 8 KB  -> total 40960
    const int bx = blockIdx.x;
    const int qt = 31 - (bx >> 5);                // heavy tiles first
    const int bh = bx & 31;
    const int h = bh & 15, b = bh >> 4;
    const int tid = threadIdx.x;
    const int wave = tid >> 6, lane = tid & 63;
    const int l15 = lane & 15, quad = lane >> 4;
    const int m0w = qt * 64 + wave * 16;
    const size_t bhoff = (size_t)(b * Hc + h);
    const unsigned short* qh = q + bhoff * Tc * CAc;
    const unsigned short* kh = k + bhoff * Tc * CAc;
    const unsigned short* vh = vT + bhoff * CAc * Tc;

    const int srow = (lane >> 3);
    const int sgc  = (lane & 7) ^ srow;
    const int h7 = l15 & 7;
    const int sw0 = ((quad ^ h7) << 3);
    const int sw1 = (((4 + quad) ^ h7) << 3);
    const int pw_m = 2 * h7;

    short8 qf[2];
#pragma unroll
    for (int s = 0; s < 2; s++)
        qf[s] = *(const short8*)(&qh[(size_t)(m0w + l15) * CAc + s * 32 + quad * 8]);

    f32x4 oacc[4], osum;
#pragma unroll
    for (int j2 = 0; j2 < 4; j2++) oacc[j2] = (f32x4){0.f, 0.f, 0.f, 0.f};
    osum = (f32x4){0.f, 0.f, 0.f, 0.f};

    const unsigned short ONE = 0x3F80;
    short8 ones;
#pragma unroll
    for (int i = 0; i < 8; i++) ones[i] = (short)ONE;

    unsigned short* Pw = &Pl[wave][0];

#pragma unroll
    for (int t = 0; t < 2; t++) {
        int rl = wave * 16 + t * 8;
        async_cp16(kh + (size_t)(rl + srow) * CAc + sgc * 8, &Kl[0][rl * 64]);
        async_cp16(vh + (size_t)(rl + srow) * Tc  + sgc * 8, &Vl[0][rl * 64]);
    }
    __syncthreads();

    for (int kt = 0; kt <= qt; kt++) {
        const int k0 = kt * 64;
        const int cur = kt & 1;
        if (kt < qt) {
            const unsigned short* kg = kh + (size_t)(k0 + 64) * CAc;
            const unsigned short* vg = vh + (k0 + 64);
#pragma unroll
            for (int t = 0; t < 2; t++) {
                int rl = wave * 16 + t * 8;
                async_cp16(kg + (size_t)(rl + srow) * CAc + sgc * 8, &Kl[1 - cur][rl * 64]);
                async_cp16(vg + (size_t)(rl + srow) * Tc  + sgc * 8, &Vl[1 - cur][rl * 64]);
            }
        }
        const unsigned short* Kc = Kl[cur];
        const unsigned short* Vc = Vl[cur];

        float sv[4][4];
#pragma unroll
        for (int j = 0; j < 4; j++) {
            short8 kf0 = *(const short8*)(&Kc[(j * 16 + l15) * 64 + sw0]);
            short8 kf1 = *(const short8*)(&Kc[(j * 16 + l15) * 64 + sw1]);
            f32x4 z = (f32x4){0.f, 0.f, 0.f, 0.f};
            z = __builtin_amdgcn_mfma_f32_16x16x32_bf16(kf0, qf[0], z, 0, 0, 0);
            z = __builtin_amdgcn_mfma_f32_16x16x32_bf16(kf1, qf[1], z, 0, 0, 0);
#pragma unroll
            for (int r = 0; r < 4; r++) sv[j][r] = z[r];
        }

        if (kt == qt) {
            int tg = m0w + l15;
#pragma unroll
            for (int j = 0; j < 4; j++)
#pragma unroll
                for (int r = 0; r < 4; r++) {
                    int sg = k0 + j * 16 + quad * 4 + r;
                    sv[j][r] = (sg <= tg) ? __builtin_amdgcn_exp2f(sv[j][r]) : 0.f;
                }
        } else {
#pragma unroll
            for (int j = 0; j < 4; j++)
#pragma unroll
                for (int r = 0; r < 4; r++)
                    sv[j][r] = __builtin_amdgcn_exp2f(sv[j][r]);
        }

        short8 pa[2];
#pragma unroll
        for (int j = 0; j < 4; j++) {
            uint2 v;
            v.x = pack_trunc(sv[j][0], sv[j][1]);
            v.y = pack_trunc(sv[j][2], sv[j][3]);
            *(uint2*)(&Pw[l15 * 64 + ((j * 4 + quad) ^ pw_m) * 4]) = v;
        }
#pragma unroll
        for (int c = 0; c < 2; c++)
            pa[c] = *(const short8*)(&Pw[l15 * 64 + ((c * 4 + quad) ^ h7) * 8]);

#pragma unroll
        for (int c = 0; c < 2; c++) {
#pragma unroll
            for (int j2 = 0; j2 < 4; j2++) {
                short8 vb = *(const short8*)(&Vc[(j2 * 16 + l15) * 64 + (c ? sw1 : sw0)]);
                oacc[j2] = __builtin_amdgcn_mfma_f32_16x16x32_bf16(pa[c], vb, oacc[j2], 0, 0, 0);
            }
            osum = __builtin_amdgcn_mfma_f32_16x16x32_bf16(pa[c], ones, osum, 0, 0, 0);
        }
        __syncthreads();
    }

    float ri[4];
#pragma unroll
    for (int r = 0; r < 4; r++) ri[r] = 1.0f / osum[r];
#pragma unroll
    for (int j2 = 0; j2 < 4; j2++) {
#pragma unroll
        for (int r = 0; r < 4; r++) {
            int t = m0w + quad * 4 + r;
            y[((size_t)b * Tc + t) * Cn + h * CAc + j2 * 16 + l15] = f2bf(oacc[j2][r] * ri[r]);
        }
    }
}

// ---------------------------------------------------------------------------
extern "C" void kernel_launch(void* const* d_in, const int* in_sizes, int n_in,
                              void* d_out, int out_size, void* d_ws, size_t ws_size,
                              hipStream_t stream) {
    const void* x  = d_in[0];
    const void* wq = d_in[1];
    const void* wk = d_in[2];
    const void* wv = d_in[3];
    const void* wo = d_in[4];
    char* ws = (char*)d_ws;
    // ws layout (MB): wT@1(6) | woT@7(2) | xb@9(8) | q@17(8) | k@25(8) | vT@33(8) | y@41(8)
    unsigned short* wT  = (unsigned short*)(ws + ((size_t)1 << 20));
    unsigned short* woT = (unsigned short*)(ws + ((size_t)7 << 20));
    unsigned short* xb  = (unsigned short*)(ws + ((size_t)9 << 20));
    unsigned short* qb  = (unsigned short*)(ws + ((size_t)17 << 20));
    unsigned short* kb  = (unsigned short*)(ws + ((size_t)25 << 20));
    unsigned short* vTb = (unsigned short*)(ws + ((size_t)33 << 20));
    unsigned short* yb  = (unsigned short*)(ws + ((size_t)41 << 20));

    prep<<<dim3(8192), dim3(256), 0, stream>>>(x, xb, wq, wk, wv, wo, wT, woT);
    gemm_qkv<<<dim3(24, 32), dim3(128), 0, stream>>>(x, xb, wT, qb, kb, vTb);
    attn_t<<<dim3(1024), dim3(256), 0, stream>>>(qb, kb, vTb, yb);
    gemm_out<<<dim3(8, 64), dim3(256), 0, stream>>>(yb, woT, d_out, x);
}